// Round 19
// baseline (140.411 us; speedup 1.0000x reference)
//
#include <hip/hip_runtime.h>
#include <hip/hip_bf16.h>

// out[b,i,k] = sum_j tanh(bn2( relu(bn1( [x_i,x_j,adj_ij] @ W1 )) @ W2 ))[k]
// Double-buffered pipeline, 1 barrier/tile:
//   iter jt: load(jt+1) ; phase2-MFMA(jt) [setprio] ; phase1(jt+1) ;
//            tanh-finish(jt) [overlaps phase1 in scheduler] ; barrier
// Phase-1 (swapped): D[h][j] = mfma(A=W1a^T, B=adj-from-global) + P1; += P2 (pk_add), relu.
// Phase-2: h1b @ W2 (persistent register frags bB2[2][8]); tanh via builtin v_exp_f32.

typedef short short8 __attribute__((ext_vector_type(8)));
typedef float f32x4 __attribute__((ext_vector_type(4)));
typedef unsigned int u32x2 __attribute__((ext_vector_type(2)));
typedef unsigned int u32x4 __attribute__((ext_vector_type(4)));

#define EPSV 1e-5f
#define TWO_LOG2E 2.885390081777927f
#define H1STRIDE 264

// ws float offsets
#define OFF_P1T  0         // [1024][256] f32
#define OFF_P2S  262144    // [1024][256] f32 row-major ([b*512+j][h])
#define OFF_S1   524288
#define OFF_T1   524544
#define OFF_T2   524800    // t2 * 2log2e
#define OFF_W1F  525056    // bf16 frags [16][64][8] (k>=16 zero) = 4096 floats
#define OFF_W2F  529152    // bf16 frags [128][64][8] = 32768 floats

__device__ __forceinline__ short f2bf(float f) {
    unsigned u = __builtin_bit_cast(unsigned, f);
    u += 0x7fffu + ((u >> 16) & 1u);
    return (short)(u >> 16);
}

__device__ __forceinline__ unsigned pk2bf(float lo, float hi) {
    unsigned u;
    asm("v_cvt_pk_bf16_f32 %0, %1, %2" : "=v"(u) : "v"(lo), "v"(hi));
    return u;
}

__device__ __forceinline__ float fexp2(float x) {
#if __has_builtin(__builtin_amdgcn_exp2f)
    return __builtin_amdgcn_exp2f(x);
#else
    return exp2f(x);
#endif
}

__global__ void prep_scalars(const float* __restrict__ g1, const float* __restrict__ b1,
                             const float* __restrict__ m1, const float* __restrict__ v1,
                             const float* __restrict__ g2, const float* __restrict__ b2,
                             const float* __restrict__ m2, const float* __restrict__ v2,
                             float* __restrict__ wsf) {
    int t = threadIdx.x;  // h (0..255)
    float s1 = g1[t] * __frsqrt_rn(v1[t] + EPSV);
    float t1 = b1[t] - m1[t] * s1;
    float s2 = g2[t] * __frsqrt_rn(v2[t] + EPSV);
    float t2 = b2[t] - m2[t] * s2;
    wsf[OFF_S1 + t] = s1;
    wsf[OFF_T1 + t] = t1;
    wsf[OFF_T2 + t] = t2 * TWO_LOG2E;
}

// W1a fragments [16][64][8]: frag f, lane l: h-col=(f>>1)*32+(f&1)*16+(l&15),
// k=(l>>4)*8+e (k<16 real, else 0), val = W1[(256+k)*256+h]*s1[h]
__global__ void prep_w1f(const float* __restrict__ W1, float* __restrict__ wsf) {
    int tid = blockIdx.x * 256 + threadIdx.x;  // 0..1023
    int f = tid >> 6, l = tid & 63;
    int col = (f >> 1) * 32 + (f & 1) * 16 + (l & 15);
    int kb = (l >> 4) * 8;
    float s1 = wsf[OFF_S1 + col];
    short8 v;
#pragma unroll
    for (int e = 0; e < 8; ++e) {
        int k = kb + e;
        v[e] = (k < 16) ? f2bf(W1[(256 + k) * 256 + col] * s1) : (short)0;
    }
    *(short8*)((short*)(wsf + OFF_W1F) + tid * 8) = v;
}

// W2 fragments [128][64][8]: frag f = w*16+n*8+s, lane l: col = w*32+n*16+(l&15),
// k = s*32+(l>>4)*8+e, val = W2[k*256+col]*s2[col]*2log2e
__global__ void prep_w2f(const float* __restrict__ W2,
                         const float* __restrict__ g2, const float* __restrict__ v2,
                         float* __restrict__ wsf) {
    int tid = blockIdx.x * 256 + threadIdx.x;  // 0..8191
    int f = tid >> 6, l = tid & 63;
    int w = f >> 4, n = (f >> 3) & 1, s = f & 7;
    int col = w * 32 + n * 16 + (l & 15);
    int kb = s * 32 + (l >> 4) * 8;
    float s2 = g2[col] * __frsqrt_rn(v2[col] + EPSV) * TWO_LOG2E;
    short8 v;
#pragma unroll
    for (int e = 0; e < 8; ++e)
        v[e] = f2bf(W2[(kb + e) * 256 + col] * s2);
    *(short8*)((short*)(wsf + OFF_W2F) + tid * 8) = v;
}

// P1t f32 + P2S f32 row-major
__global__ void prep_p(const float* __restrict__ inp, const float* __restrict__ W1,
                       float* __restrict__ wsf) {
    int bn = blockIdx.x, h = threadIdx.x;
    const float* x = inp + (size_t)bn * 128;
    float a1 = 0.f, a2 = 0.f;
    for (int c = 0; c < 128; ++c) {
        float xv = x[c];
        a1 = fmaf(xv, W1[c * 256 + h], a1);
        a2 = fmaf(xv, W1[(128 + c) * 256 + h], a2);
    }
    float s1 = wsf[OFF_S1 + h], t1 = wsf[OFF_T1 + h];
    wsf[OFF_P1T + (size_t)bn * 256 + h] = a1 * s1 + t1;
    wsf[OFF_P2S + (size_t)bn * 256 + h] = a2 * s1;
}

__global__ __launch_bounds__(512, 2) void propmain(
    const float* __restrict__ adj, const float* __restrict__ wsf,
    float* __restrict__ out) {
    __shared__ __align__(16) short h1b[2][64 * H1STRIDE];  // 2 x 33 KB, padded rows

    const int bi = blockIdx.x;
    const int b = bi >> 9;
    const int t = threadIdx.x;
    const int w = t >> 6, l = t & 63, r = l & 15, q = l >> 4;

    const float* P1t = wsf + OFF_P1T;
    const float* P2s = wsf + OFF_P2S + (size_t)b * 512 * 256;
    const float* t2p = wsf + OFF_T2;
    const short* W1f = (const short*)(wsf + OFF_W1F);
    const short* W2f = (const short*)(wsf + OFF_W2F);

    // persistent fragments: W1a^T (8 VGPR) + W2 slice (64 VGPR)
    const short* w1fw = W1f + (w * 2) * 512 + l * 8;
    const short8 aW1_0 = *(const short8*)(w1fw);
    const short8 aW1_1 = *(const short8*)(w1fw + 512);
    short8 bB2[2][8];
    f32x4 p1v[2];
    float t2v[2];
#pragma unroll
    for (int n = 0; n < 2; ++n) {
#pragma unroll
        for (int s = 0; s < 8; ++s)
            bB2[n][s] = *(const short8*)(W2f + ((w * 16 + n * 8 + s) * 64 + l) * 8);
        p1v[n] = *(const f32x4*)(P1t + (size_t)bi * 256 + w * 32 + n * 16 + q * 4);
        t2v[n] = t2p[w * 32 + n * 16 + r];
    }

    // per-lane adj address (valid for q<2): row jb*16+r, k-chunk q*8
    const float* adjlane = adj + (size_t)bi * 8192 + r * 16 + q * 8;
    // per-lane P2 base: row j = r (+tile offsets), cols w*32+q*4 (+na*16)
    const float* p2base = P2s + (size_t)r * 256 + w * 32 + q * 4;

    // staging registers for tile jt+1
    float4 adjr[4][2];
    f32x4 p2f[2][4];

#define LOAD_TILE(JTN) do {                                                     \
        if (q < 2) {                                                            \
            _Pragma("unroll")                                                   \
            for (int jb = 0; jb < 4; ++jb) {                                    \
                adjr[jb][0] = *(const float4*)(adjlane + (JTN) * 1024 + jb * 256);      \
                adjr[jb][1] = *(const float4*)(adjlane + (JTN) * 1024 + jb * 256 + 4);  \
            }                                                                   \
        }                                                                       \
        _Pragma("unroll")                                                       \
        for (int na = 0; na < 2; ++na)                                          \
            _Pragma("unroll")                                                   \
            for (int jb = 0; jb < 4; ++jb)                                      \
                p2f[na][jb] = *(const f32x4*)(p2base +                          \
                    (size_t)((JTN) * 64 + jb * 16) * 256 + na * 16);            \
    } while (0)

#define PHASE1(H1DST) do {                                                      \
        f32x4 acc1[2][4];                                                       \
        _Pragma("unroll")                                                       \
        for (int na = 0; na < 2; ++na)                                          \
            _Pragma("unroll")                                                   \
            for (int jb = 0; jb < 4; ++jb) acc1[na][jb] = p1v[na];              \
        _Pragma("unroll")                                                       \
        for (int jb = 0; jb < 4; ++jb) {                                        \
            short8 badj;                                                        \
            if (q < 2) {                                                        \
                u32x4 uv;                                                       \
                uv.x = pk2bf(adjr[jb][0].x, adjr[jb][0].y);                     \
                uv.y = pk2bf(adjr[jb][0].z, adjr[jb][0].w);                     \
                uv.z = pk2bf(adjr[jb][1].x, adjr[jb][1].y);                     \
                uv.w = pk2bf(adjr[jb][1].z, adjr[jb][1].w);                     \
                badj = __builtin_bit_cast(short8, uv);                          \
            } else {                                                            \
                badj = (short8){0, 0, 0, 0, 0, 0, 0, 0};                        \
            }                                                                   \
            acc1[0][jb] = __builtin_amdgcn_mfma_f32_16x16x32_bf16(              \
                aW1_0, badj, acc1[0][jb], 0, 0, 0);                             \
            acc1[1][jb] = __builtin_amdgcn_mfma_f32_16x16x32_bf16(              \
                aW1_1, badj, acc1[1][jb], 0, 0, 0);                             \
        }                                                                       \
        _Pragma("unroll")                                                       \
        for (int na = 0; na < 2; ++na)                                          \
            _Pragma("unroll")                                                   \
            for (int jb = 0; jb < 4; ++jb) {                                    \
                const int j = jb * 16 + r;                                      \
                const f32x4 yv = acc1[na][jb] + p2f[na][jb];  /* pk_add x2 */   \
                const float y0 = fmaxf(yv.x, 0.f);                              \
                const float y1 = fmaxf(yv.y, 0.f);                              \
                const float y2 = fmaxf(yv.z, 0.f);                              \
                const float y3 = fmaxf(yv.w, 0.f);                              \
                u32x2 pk;                                                       \
                pk.x = pk2bf(y0, y1);                                           \
                pk.y = pk2bf(y2, y3);                                           \
                const int colb = w * 32 + na * 16 + q * 4;                      \
                *(u32x2*)((H1DST) + j * H1STRIDE + colb) = pk;                  \
            }                                                                   \
    } while (0)

    float part[2] = {0.f, 0.f};

    // prologue: stage + compute tile 0 into h1b[0]
    LOAD_TILE(0);
    PHASE1(h1b[0]);
    __syncthreads();

    for (int jt = 0; jt < 8; ++jt) {
        const short* h1cur = h1b[jt & 1];
        short* h1nxt = h1b[(jt + 1) & 1];

        if (jt < 7) LOAD_TILE(jt + 1);  // global->reg, hides under phase 2

        // ---- phase 2(jt) MFMA: h1cur @ bB2 (64 MFMA) -> acc ----
        f32x4 acc[4][2];
#pragma unroll
        for (int rf = 0; rf < 4; ++rf)
#pragma unroll
            for (int n = 0; n < 2; ++n)
                acc[rf][n] = (f32x4){t2v[n], t2v[n], t2v[n], t2v[n]};
        __builtin_amdgcn_s_setprio(1);
#pragma unroll
        for (int s = 0; s < 8; ++s) {
#pragma unroll
            for (int rf = 0; rf < 4; ++rf) {
                const int row = rf * 16 + r;
                const short8 aA = *(const short8*)(
                    h1cur + row * H1STRIDE + s * 32 + q * 8);
                acc[rf][0] = __builtin_amdgcn_mfma_f32_16x16x32_bf16(
                    aA, bB2[0][s], acc[rf][0], 0, 0, 0);
                acc[rf][1] = __builtin_amdgcn_mfma_f32_16x16x32_bf16(
                    aA, bB2[1][s], acc[rf][1], 0, 0, 0);
            }
        }
        __builtin_amdgcn_s_setprio(0);

        // ---- phase 1(jt+1): consume staged regs -> h1nxt ----
        if (jt < 7) PHASE1(h1nxt);

        // ---- tanh finish(jt): overlaps phase-1 in the scheduler ----
#pragma unroll
        for (int n = 0; n < 2; ++n) {
            float ps = 0.f;
#pragma unroll
            for (int rf = 0; rf < 4; ++rf)
#pragma unroll
                for (int e = 0; e < 4; ++e) {
                    const float ex = fexp2(acc[rf][n][e]);
                    ps += __builtin_amdgcn_rcpf(ex + 1.f);
                }
            part[n] += ps;
        }

        __syncthreads();  // h1nxt complete; h1cur reads done
    }

    // sum_j tanh = 512 - 2*sum(rcp); reduce over q
#pragma unroll
    for (int n = 0; n < 2; ++n) {
        float v = part[n];
        v += __shfl_xor(v, 16, 64);
        v += __shfl_xor(v, 32, 64);
        if (q == 0) out[(size_t)bi * 256 + w * 32 + n * 16 + r] = 512.f - 2.f * v;
    }
#undef LOAD_TILE
#undef PHASE1
}

extern "C" void kernel_launch(void* const* d_in, const int* in_sizes, int n_in,
                              void* d_out, int out_size, void* d_ws, size_t ws_size,
                              hipStream_t stream) {
    (void)in_sizes; (void)n_in; (void)out_size; (void)ws_size;
    const float* inputs = (const float*)d_in[0];
    const float* adj    = (const float*)d_in[1];
    const float* W1     = (const float*)d_in[2];
    const float* g1     = (const float*)d_in[3];
    const float* b1     = (const float*)d_in[4];
    const float* m1     = (const float*)d_in[5];
    const float* v1     = (const float*)d_in[6];
    const float* W2     = (const float*)d_in[7];
    const float* g2     = (const float*)d_in[8];
    const float* b2     = (const float*)d_in[9];
    const float* m2     = (const float*)d_in[10];
    const float* v2     = (const float*)d_in[11];
    float* out = (float*)d_out;
    float* wsf = (float*)d_ws;

    prep_scalars<<<1, 256, 0, stream>>>(g1, b1, m1, v1, g2, b2, m2, v2, wsf);
    prep_w1f<<<4, 256, 0, stream>>>(W1, wsf);
    prep_w2f<<<32, 256, 0, stream>>>(W2, g2, v2, wsf);
    prep_p<<<1024, 256, 0, stream>>>(inputs, W1, wsf);
    propmain<<<1024, 512, 0, stream>>>(adj, wsf, out);
}

// Round 21
// 133.797 us; speedup vs baseline: 1.0494x; 1.0494x over previous
//
#include <hip/hip_runtime.h>
#include <hip/hip_bf16.h>

// out[b,i,k] = sum_j tanh(bn2( relu(bn1( [x_i,x_j,adj_ij] @ W1 )) @ W2 ))[k]
// R18 structure (dbuf, 1 barrier/tile) + prefetch pin:
//   iter jt: load(jt+1) ; [mem clobber] ; phase2(jt)+tanh ; phase1(jt+1) ; barrier
// Phase-1 (swapped): D[h][j] = mfma(W1a^T, adj) + P1; += P2 (pk_add), relu -> bf16 LDS.
// Phase-2: h1b @ W2 (persistent register frags bB2[2][8]); tanh via builtin v_exp_f32.

typedef short short8 __attribute__((ext_vector_type(8)));
typedef float f32x4 __attribute__((ext_vector_type(4)));
typedef unsigned int u32x2 __attribute__((ext_vector_type(2)));
typedef unsigned int u32x4 __attribute__((ext_vector_type(4)));

#define EPSV 1e-5f
#define TWO_LOG2E 2.885390081777927f
#define H1STRIDE 264

// ws float offsets
#define OFF_P1T  0         // [1024][256] f32
#define OFF_P2S  262144    // [1024][256] f32 row-major ([b*512+j][h])
#define OFF_S1   524288
#define OFF_T1   524544
#define OFF_T2   524800    // t2 * 2log2e
#define OFF_W1F  525056    // bf16 frags [16][64][8] (k>=16 zero) = 4096 floats
#define OFF_W2F  529152    // bf16 frags [128][64][8] = 32768 floats

__device__ __forceinline__ short f2bf(float f) {
    unsigned u = __builtin_bit_cast(unsigned, f);
    u += 0x7fffu + ((u >> 16) & 1u);
    return (short)(u >> 16);
}

__device__ __forceinline__ unsigned pk2bf(float lo, float hi) {
    unsigned u;
    asm("v_cvt_pk_bf16_f32 %0, %1, %2" : "=v"(u) : "v"(lo), "v"(hi));
    return u;
}

__device__ __forceinline__ float fexp2(float x) {
#if __has_builtin(__builtin_amdgcn_exp2f)
    return __builtin_amdgcn_exp2f(x);
#else
    return exp2f(x);
#endif
}

__global__ void prep_scalars(const float* __restrict__ g1, const float* __restrict__ b1,
                             const float* __restrict__ m1, const float* __restrict__ v1,
                             const float* __restrict__ g2, const float* __restrict__ b2,
                             const float* __restrict__ m2, const float* __restrict__ v2,
                             float* __restrict__ wsf) {
    int t = threadIdx.x;  // h (0..255)
    float s1 = g1[t] * __frsqrt_rn(v1[t] + EPSV);
    float t1 = b1[t] - m1[t] * s1;
    float s2 = g2[t] * __frsqrt_rn(v2[t] + EPSV);
    float t2 = b2[t] - m2[t] * s2;
    wsf[OFF_S1 + t] = s1;
    wsf[OFF_T1 + t] = t1;
    wsf[OFF_T2 + t] = t2 * TWO_LOG2E;
}

// W1a fragments [16][64][8]: frag f, lane l: h-col=(f>>1)*32+(f&1)*16+(l&15),
// k=(l>>4)*8+e (k<16 real, else 0), val = W1[(256+k)*256+h]*s1[h]
__global__ void prep_w1f(const float* __restrict__ W1, float* __restrict__ wsf) {
    int tid = blockIdx.x * 256 + threadIdx.x;  // 0..1023
    int f = tid >> 6, l = tid & 63;
    int col = (f >> 1) * 32 + (f & 1) * 16 + (l & 15);
    int kb = (l >> 4) * 8;
    float s1 = wsf[OFF_S1 + col];
    short8 v;
#pragma unroll
    for (int e = 0; e < 8; ++e) {
        int k = kb + e;
        v[e] = (k < 16) ? f2bf(W1[(256 + k) * 256 + col] * s1) : (short)0;
    }
    *(short8*)((short*)(wsf + OFF_W1F) + tid * 8) = v;
}

// W2 fragments [128][64][8]: frag f = w*16+n*8+s, lane l: col = w*32+n*16+(l&15),
// k = s*32+(l>>4)*8+e, val = W2[k*256+col]*s2[col]*2log2e
__global__ void prep_w2f(const float* __restrict__ W2,
                         const float* __restrict__ g2, const float* __restrict__ v2,
                         float* __restrict__ wsf) {
    int tid = blockIdx.x * 256 + threadIdx.x;  // 0..8191
    int f = tid >> 6, l = tid & 63;
    int w = f >> 4, n = (f >> 3) & 1, s = f & 7;
    int col = w * 32 + n * 16 + (l & 15);
    int kb = s * 32 + (l >> 4) * 8;
    float s2 = g2[col] * __frsqrt_rn(v2[col] + EPSV) * TWO_LOG2E;
    short8 v;
#pragma unroll
    for (int e = 0; e < 8; ++e)
        v[e] = f2bf(W2[(kb + e) * 256 + col] * s2);
    *(short8*)((short*)(wsf + OFF_W2F) + tid * 8) = v;
}

// P1t f32 + P2S f32 row-major
__global__ void prep_p(const float* __restrict__ inp, const float* __restrict__ W1,
                       float* __restrict__ wsf) {
    int bn = blockIdx.x, h = threadIdx.x;
    const float* x = inp + (size_t)bn * 128;
    float a1 = 0.f, a2 = 0.f;
    for (int c = 0; c < 128; ++c) {
        float xv = x[c];
        a1 = fmaf(xv, W1[c * 256 + h], a1);
        a2 = fmaf(xv, W1[(128 + c) * 256 + h], a2);
    }
    float s1 = wsf[OFF_S1 + h], t1 = wsf[OFF_T1 + h];
    wsf[OFF_P1T + (size_t)bn * 256 + h] = a1 * s1 + t1;
    wsf[OFF_P2S + (size_t)bn * 256 + h] = a2 * s1;
}

__global__ __launch_bounds__(512, 2) void propmain(
    const float* __restrict__ adj, const float* __restrict__ wsf,
    float* __restrict__ out) {
    __shared__ __align__(16) short h1b[2][64 * H1STRIDE];  // 2 x 33 KB, padded rows

    const int bi = blockIdx.x;
    const int b = bi >> 9;
    const int t = threadIdx.x;
    const int w = t >> 6, l = t & 63, r = l & 15, q = l >> 4;

    const float* P1t = wsf + OFF_P1T;
    const float* P2s = wsf + OFF_P2S + (size_t)b * 512 * 256;
    const float* t2p = wsf + OFF_T2;
    const short* W1f = (const short*)(wsf + OFF_W1F);
    const short* W2f = (const short*)(wsf + OFF_W2F);

    // persistent fragments: W1a^T (8 VGPR) + W2 slice (64 VGPR)
    const short* w1fw = W1f + (w * 2) * 512 + l * 8;
    const short8 aW1_0 = *(const short8*)(w1fw);
    const short8 aW1_1 = *(const short8*)(w1fw + 512);
    short8 bB2[2][8];
    f32x4 p1v[2];
    float t2v[2];
#pragma unroll
    for (int n = 0; n < 2; ++n) {
#pragma unroll
        for (int s = 0; s < 8; ++s)
            bB2[n][s] = *(const short8*)(W2f + ((w * 16 + n * 8 + s) * 64 + l) * 8);
        p1v[n] = *(const f32x4*)(P1t + (size_t)bi * 256 + w * 32 + n * 16 + q * 4);
        t2v[n] = t2p[w * 32 + n * 16 + r];
    }

    // per-lane adj address (valid for q<2): row jb*16+r, k-chunk q*8
    const float* adjlane = adj + (size_t)bi * 8192 + r * 16 + q * 8;
    // per-lane P2 base: row j = r (+tile offsets), cols w*32+q*4 (+na*16)
    const float* p2base = P2s + (size_t)r * 256 + w * 32 + q * 4;

    // staging registers for tile jt+1
    float4 adjr[4][2];
    f32x4 p2f[2][4];

#define LOAD_TILE(JTN) do {                                                     \
        if (q < 2) {                                                            \
            _Pragma("unroll")                                                   \
            for (int jb = 0; jb < 4; ++jb) {                                    \
                adjr[jb][0] = *(const float4*)(adjlane + (JTN) * 1024 + jb * 256);      \
                adjr[jb][1] = *(const float4*)(adjlane + (JTN) * 1024 + jb * 256 + 4);  \
            }                                                                   \
        }                                                                       \
        _Pragma("unroll")                                                       \
        for (int na = 0; na < 2; ++na)                                          \
            _Pragma("unroll")                                                   \
            for (int jb = 0; jb < 4; ++jb)                                      \
                p2f[na][jb] = *(const f32x4*)(p2base +                          \
                    (size_t)((JTN) * 64 + jb * 16) * 256 + na * 16);            \
    } while (0)

#define PHASE1(H1DST) do {                                                      \
        f32x4 acc1[2][4];                                                       \
        _Pragma("unroll")                                                       \
        for (int na = 0; na < 2; ++na)                                          \
            _Pragma("unroll")                                                   \
            for (int jb = 0; jb < 4; ++jb) acc1[na][jb] = p1v[na];              \
        _Pragma("unroll")                                                       \
        for (int jb = 0; jb < 4; ++jb) {                                        \
            short8 badj;                                                        \
            if (q < 2) {                                                        \
                u32x4 uv;                                                       \
                uv.x = pk2bf(adjr[jb][0].x, adjr[jb][0].y);                     \
                uv.y = pk2bf(adjr[jb][0].z, adjr[jb][0].w);                     \
                uv.z = pk2bf(adjr[jb][1].x, adjr[jb][1].y);                     \
                uv.w = pk2bf(adjr[jb][1].z, adjr[jb][1].w);                     \
                badj = __builtin_bit_cast(short8, uv);                          \
            } else {                                                            \
                badj = (short8){0, 0, 0, 0, 0, 0, 0, 0};                        \
            }                                                                   \
            acc1[0][jb] = __builtin_amdgcn_mfma_f32_16x16x32_bf16(              \
                aW1_0, badj, acc1[0][jb], 0, 0, 0);                             \
            acc1[1][jb] = __builtin_amdgcn_mfma_f32_16x16x32_bf16(              \
                aW1_1, badj, acc1[1][jb], 0, 0, 0);                             \
        }                                                                       \
        _Pragma("unroll")                                                       \
        for (int na = 0; na < 2; ++na)                                          \
            _Pragma("unroll")                                                   \
            for (int jb = 0; jb < 4; ++jb) {                                    \
                const int j = jb * 16 + r;                                      \
                const f32x4 yv = acc1[na][jb] + p2f[na][jb];  /* pk_add x2 */   \
                const float y0 = fmaxf(yv.x, 0.f);                              \
                const float y1 = fmaxf(yv.y, 0.f);                              \
                const float y2 = fmaxf(yv.z, 0.f);                              \
                const float y3 = fmaxf(yv.w, 0.f);                              \
                u32x2 pk;                                                       \
                pk.x = pk2bf(y0, y1);                                           \
                pk.y = pk2bf(y2, y3);                                           \
                const int colb = w * 32 + na * 16 + q * 4;                      \
                *(u32x2*)((H1DST) + j * H1STRIDE + colb) = pk;                  \
            }                                                                   \
    } while (0)

    float part[2] = {0.f, 0.f};

    // prologue: stage + compute tile 0 into h1b[0]
    LOAD_TILE(0);
    PHASE1(h1b[0]);
    __syncthreads();

    for (int jt = 0; jt < 8; ++jt) {
        const short* h1cur = h1b[jt & 1];
        short* h1nxt = h1b[(jt + 1) & 1];

        if (jt < 7) LOAD_TILE(jt + 1);  // global->reg prefetch
        asm volatile("" ::: "memory");  // pin: loads may not sink below this

        // ---- phase 2(jt): h1cur @ bB2 (64 MFMA), tanh finish ----
        {
            f32x4 acc[4][2];
#pragma unroll
            for (int rf = 0; rf < 4; ++rf)
#pragma unroll
                for (int n = 0; n < 2; ++n)
                    acc[rf][n] = (f32x4){t2v[n], t2v[n], t2v[n], t2v[n]};
#pragma unroll
            for (int s = 0; s < 8; ++s) {
#pragma unroll
                for (int rf = 0; rf < 4; ++rf) {
                    const int row = rf * 16 + r;
                    const short8 aA = *(const short8*)(
                        h1cur + row * H1STRIDE + s * 32 + q * 8);
                    acc[rf][0] = __builtin_amdgcn_mfma_f32_16x16x32_bf16(
                        aA, bB2[0][s], acc[rf][0], 0, 0, 0);
                    acc[rf][1] = __builtin_amdgcn_mfma_f32_16x16x32_bf16(
                        aA, bB2[1][s], acc[rf][1], 0, 0, 0);
                }
            }
#pragma unroll
            for (int n = 0; n < 2; ++n) {
                float ps = 0.f;
#pragma unroll
                for (int rf = 0; rf < 4; ++rf)
#pragma unroll
                    for (int e = 0; e < 4; ++e) {
                        const float ex = fexp2(acc[rf][n][e]);
                        ps += __builtin_amdgcn_rcpf(ex + 1.f);
                    }
                part[n] += ps;
            }
        }

        // ---- phase 1(jt+1): consume staged regs -> h1nxt ----
        if (jt < 7) PHASE1(h1nxt);

        __syncthreads();  // h1nxt complete; h1cur reads done
    }

    // sum_j tanh = 512 - 2*sum(rcp); reduce over q
#pragma unroll
    for (int n = 0; n < 2; ++n) {
        float v = part[n];
        v += __shfl_xor(v, 16, 64);
        v += __shfl_xor(v, 32, 64);
        if (q == 0) out[(size_t)bi * 256 + w * 32 + n * 16 + r] = 512.f - 2.f * v;
    }
#undef LOAD_TILE
#undef PHASE1
}

extern "C" void kernel_launch(void* const* d_in, const int* in_sizes, int n_in,
                              void* d_out, int out_size, void* d_ws, size_t ws_size,
                              hipStream_t stream) {
    (void)in_sizes; (void)n_in; (void)out_size; (void)ws_size;
    const float* inputs = (const float*)d_in[0];
    const float* adj    = (const float*)d_in[1];
    const float* W1     = (const float*)d_in[2];
    const float* g1     = (const float*)d_in[3];
    const float* b1     = (const float*)d_in[4];
    const float* m1     = (const float*)d_in[5];
    const float* v1     = (const float*)d_in[6];
    const float* W2     = (const float*)d_in[7];
    const float* g2     = (const float*)d_in[8];
    const float* b2     = (const float*)d_in[9];
    const float* m2     = (const float*)d_in[10];
    const float* v2     = (const float*)d_in[11];
    float* out = (float*)d_out;
    float* wsf = (float*)d_ws;

    prep_scalars<<<1, 256, 0, stream>>>(g1, b1, m1, v1, g2, b2, m2, v2, wsf);
    prep_w1f<<<4, 256, 0, stream>>>(W1, wsf);
    prep_w2f<<<32, 256, 0, stream>>>(W2, g2, v2, wsf);
    prep_p<<<1024, 256, 0, stream>>>(inputs, W1, wsf);
    propmain<<<1024, 512, 0, stream>>>(adj, wsf, out);
}